// Round 1
// baseline (372.287 us; speedup 1.0000x reference)
//
#include <hip/hip_runtime.h>
#include <cstdint>
#include <cstddef>

#define WS_ALIGN(x) (((x) + 255) & ~(size_t)255)

// ---------- CSR build ----------

__global__ __launch_bounds__(256) void k_zero_cnt(int* __restrict__ cnt, int N) {
  int i = blockIdx.x * 256 + threadIdx.x;
  if (i < N) cnt[i] = 0;
}

__global__ __launch_bounds__(256) void k_count(const int* __restrict__ dst, int* __restrict__ cnt, int E) {
  int e = blockIdx.x * 256 + threadIdx.x;
  if (e < E) atomicAdd(&cnt[dst[e]], 1);
}

// per-block reduce of cnt -> bsum[b]; also dinv[i] = rsqrt(cnt[i]+1)  (self-loop included)
__global__ __launch_bounds__(256) void k_scanA(const int* __restrict__ cnt, int* __restrict__ bsum,
                                               float* __restrict__ dinv, int N) {
  __shared__ int s[256];
  int t = threadIdx.x;
  int i = blockIdx.x * 256 + t;
  int v = (i < N) ? cnt[i] : 0;
  if (i < N) dinv[i] = rsqrtf((float)v + 1.0f);
  s[t] = v; __syncthreads();
  for (int d = 128; d > 0; d >>= 1) {
    if (t < d) s[t] += s[t + d];
    __syncthreads();
  }
  if (t == 0) bsum[blockIdx.x] = s[0];
}

// single block: exclusive scan of bsum[nb] -> boff ; fused: transpose P1 -> P1t
__global__ __launch_bounds__(256) void k_scanB(const int* __restrict__ bsum, int* __restrict__ boff, int nb,
                                               const float* __restrict__ P1, float* __restrict__ P1t) {
  int t = threadIdx.x;
  for (int idx = t; idx < 64 * 64; idx += 256) {
    int j = idx >> 6, k = idx & 63;
    P1t[idx] = P1[k * 64 + j];   // P1t[j][k] = P1[k][j]
  }
  __shared__ int s[256];
  if (nb <= 256) {
    int v = (t < nb) ? bsum[t] : 0;
    s[t] = v; __syncthreads();
    for (int d = 1; d < 256; d <<= 1) {
      int add = (t >= d) ? s[t - d] : 0;
      __syncthreads();
      s[t] += add;
      __syncthreads();
    }
    if (t < nb) boff[t] = s[t] - v;
  } else {
    if (t == 0) { int run = 0; for (int b = 0; b < nb; ++b) { boff[b] = run; run += bsum[b]; } }
  }
}

// per-block exclusive scan + block offset -> off[i]; cursor[i] = off[i]
__global__ __launch_bounds__(256) void k_scanC(const int* __restrict__ cnt, const int* __restrict__ boff,
                                               int* __restrict__ off, int* __restrict__ cursor, int N) {
  __shared__ int s[256];
  int t = threadIdx.x;
  int i = blockIdx.x * 256 + t;
  int v = (i < N) ? cnt[i] : 0;
  s[t] = v; __syncthreads();
  for (int d = 1; d < 256; d <<= 1) {
    int add = (t >= d) ? s[t - d] : 0;
    __syncthreads();
    s[t] += add;
    __syncthreads();
  }
  int excl = s[t] - v + boff[blockIdx.x];
  if (i <= N) off[i] = excl;      // off[N] = E (total)
  if (i < N) cursor[i] = excl;
}

__global__ __launch_bounds__(256) void k_perm(const int* __restrict__ ei, int* __restrict__ cursor,
                                              int* __restrict__ perm, int E) {
  int e = blockIdx.x * 256 + threadIdx.x;
  if (e < E) {
    int d = ei[E + e];                 // dst
    int p = atomicAdd(&cursor[d], 1);
    perm[p] = ei[e];                   // src
  }
}

// ---------- GEMM: O[n][j] = (sum_k X[n][k] W[k][j]) * dinv[n]  ----------
// lane = output col j, wave handles 8 rows; X reads are wave-uniform -> scalar loads.
template<int K>
__global__ __launch_bounds__(256) void k_gemm_scale(const float* __restrict__ X, const float* __restrict__ W,
                                                    const float* __restrict__ dinv, float* __restrict__ O, int N) {
  __shared__ float Ws[K * 64];
  for (int idx = threadIdx.x; idx < K * 64; idx += 256) Ws[idx] = W[idx];
  __syncthreads();
  const int lane = threadIdx.x & 63;
  const int wg = threadIdx.x >> 6;
  int row0 = blockIdx.x * 32 + wg * 8;
  if (row0 > N - 8) row0 = N - 8;            // tail blocks recompute duplicate rows (same values)
  row0 = __builtin_amdgcn_readfirstlane(row0);
  const float* __restrict__ Xr = X + (size_t)row0 * K;
  float acc[8] = {0.f, 0.f, 0.f, 0.f, 0.f, 0.f, 0.f, 0.f};
  #pragma unroll 8
  for (int k = 0; k < K; ++k) {
    float w = Ws[k * 64 + lane];
    #pragma unroll
    for (int i = 0; i < 8; ++i)
      acc[i] = fmaf(Xr[(size_t)i * K + k], w, acc[i]);
  }
  #pragma unroll
  for (int i = 0; i < 8; ++i) {
    float dv = dinv[row0 + i];
    O[(size_t)(row0 + i) * 64 + lane] = acc[i] * dv;
  }
}

// ---------- aggregation gather: z[n] = dinv[n]*(g[n] + sum g[src]) + bias (opt. relu) ----------
template<bool RELU>
__global__ __launch_bounds__(256) void k_gather(const float* __restrict__ g, const int* __restrict__ off,
                                                const int* __restrict__ perm, const float* __restrict__ dinv,
                                                const float* __restrict__ bias, float* __restrict__ z, int N) {
  int lane = threadIdx.x & 63;
  int n = blockIdx.x * 4 + (threadIdx.x >> 6);
  if (n >= N) return;
  int s0 = off[n], s1 = off[n + 1];
  float a0 = g[(size_t)n * 64 + lane], a1 = 0.f, a2 = 0.f, a3 = 0.f;
  int p = s0;
  for (; p + 4 <= s1; p += 4) {           // 4 rows in flight for latency hiding
    int i0 = perm[p], i1 = perm[p + 1], i2 = perm[p + 2], i3 = perm[p + 3];
    a0 += g[(size_t)i0 * 64 + lane];
    a1 += g[(size_t)i1 * 64 + lane];
    a2 += g[(size_t)i2 * 64 + lane];
    a3 += g[(size_t)i3 * 64 + lane];
  }
  for (; p < s1; ++p) a0 += g[(size_t)perm[p] * 64 + lane];
  float r = dinv[n] * ((a0 + a1) + (a2 + a3)) + bias[lane];
  if (RELU) r = fmaxf(r, 0.f);
  z[(size_t)n * 64 + lane] = r;
}

// ---------- decoder: thread per label edge; weights via wave-uniform scalar loads ----------
__global__ __launch_bounds__(256) void k_decode(const float* __restrict__ z, const int* __restrict__ eli,
                                                const float* __restrict__ P1t, const float* __restrict__ pb1,
                                                const float* __restrict__ P2, const float* __restrict__ pb2,
                                                const float* __restrict__ P3, const float* __restrict__ pb3,
                                                float* __restrict__ out, int EL) {
  int e = blockIdx.x * 256 + threadIdx.x;
  if (e >= EL) return;
  int u = eli[e], v = eli[EL + e];
  const float* __restrict__ zu = z + (size_t)u * 64;
  const float* __restrict__ zv = z + (size_t)v * 64;
  float ef[64];
  #pragma unroll
  for (int k = 0; k < 64; k += 4) {
    float4 a = *(const float4*)(zu + k);
    float4 b = *(const float4*)(zv + k);
    ef[k + 0] = a.x * b.x; ef[k + 1] = a.y * b.y;
    ef[k + 2] = a.z * b.z; ef[k + 3] = a.w * b.w;
  }
  float acc2[64];
  #pragma unroll
  for (int j2 = 0; j2 < 64; ++j2) acc2[j2] = pb2[j2];
  for (int j = 0; j < 64; ++j) {          // rolled; h[j] scattered into acc2 immediately
    const float* __restrict__ p1r = P1t + j * 64;   // contiguous -> s_load_dwordx16
    float h0 = 0.f, h1 = 0.f, h2 = 0.f, h3 = 0.f;   // 4 chains for FMA-latency ILP
    #pragma unroll
    for (int k = 0; k < 64; k += 4) {
      h0 = fmaf(ef[k + 0], p1r[k + 0], h0);
      h1 = fmaf(ef[k + 1], p1r[k + 1], h1);
      h2 = fmaf(ef[k + 2], p1r[k + 2], h2);
      h3 = fmaf(ef[k + 3], p1r[k + 3], h3);
    }
    float hj = fmaxf(pb1[j] + ((h0 + h1) + (h2 + h3)), 0.f);
    const float* __restrict__ p2r = P2 + j * 64;
    #pragma unroll
    for (int j2 = 0; j2 < 64; ++j2) acc2[j2] = fmaf(hj, p2r[j2], acc2[j2]);
  }
  float r = pb3[0];
  #pragma unroll
  for (int j2 = 0; j2 < 64; ++j2) r = fmaf(fmaxf(acc2[j2], 0.f), P3[j2], r);
  out[e] = r;
}

// ---------- host ----------

extern "C" void kernel_launch(void* const* d_in, const int* in_sizes, int n_in,
                              void* d_out, int out_size, void* d_ws, size_t ws_size,
                              hipStream_t stream) {
  const float* x   = (const float*)d_in[0];
  const int*   ei  = (const int*)d_in[1];
  const int*   eli = (const int*)d_in[2];
  const float* W1  = (const float*)d_in[3];
  const float* b1  = (const float*)d_in[4];
  const float* W2  = (const float*)d_in[5];
  const float* b2  = (const float*)d_in[6];
  const float* P1  = (const float*)d_in[7];
  const float* pb1 = (const float*)d_in[8];
  const float* P2  = (const float*)d_in[9];
  const float* pb2 = (const float*)d_in[10];
  const float* P3  = (const float*)d_in[11];
  const float* pb3 = (const float*)d_in[12];
  float* out = (float*)d_out;

  const int N  = in_sizes[0] / 128;
  const int E  = in_sizes[1] / 2;
  const int EL = in_sizes[2] / 2;

  char* w = (char*)d_ws;
  auto alloc = [&](size_t bytes) { char* p = w; w += WS_ALIGN(bytes); return p; };
  int*   cnt    = (int*)  alloc((size_t)N * 4);
  int*   off    = (int*)  alloc(((size_t)N + 1) * 4);
  int*   cursor = (int*)  alloc((size_t)N * 4);
  int*   bsum   = (int*)  alloc(1024 * 4);
  int*   boff   = (int*)  alloc(1024 * 4);
  float* dinv   = (float*)alloc((size_t)N * 4);
  int*   perm   = (int*)  alloc((size_t)E * 4);
  float* P1t    = (float*)alloc(4096 * 4);
  float* bufA   = (float*)alloc((size_t)N * 64 * 4);   // g = h * dinv[row]
  float* bufB   = (float*)alloc((size_t)N * 64 * 4);   // z (layer output)

  const int nb = (N + 1 + 255) / 256;   // scan blocks cover N+1 entries (off[N]=E)

  hipLaunchKernelGGL(k_zero_cnt, dim3((N + 255) / 256), dim3(256), 0, stream, cnt, N);
  hipLaunchKernelGGL(k_count,    dim3((E + 255) / 256), dim3(256), 0, stream, ei + E, cnt, E);
  hipLaunchKernelGGL(k_scanA,    dim3(nb), dim3(256), 0, stream, cnt, bsum, dinv, N);
  hipLaunchKernelGGL(k_scanB,    dim3(1),  dim3(256), 0, stream, bsum, boff, nb, P1, P1t);
  hipLaunchKernelGGL(k_scanC,    dim3(nb), dim3(256), 0, stream, cnt, boff, off, cursor, N);
  hipLaunchKernelGGL(k_perm,     dim3((E + 255) / 256), dim3(256), 0, stream, ei, cursor, perm, E);

  // layer 1: g1 = (x@W1)*dinv ; z1 = relu(dinv*(g1[n]+sum g1[src]) + b1)
  hipLaunchKernelGGL((k_gemm_scale<128>), dim3((N + 31) / 32), dim3(256), 0, stream, x, W1, dinv, bufA, N);
  hipLaunchKernelGGL((k_gather<true>),    dim3((N + 3) / 4),   dim3(256), 0, stream, bufA, off, perm, dinv, b1, bufB, N);
  // layer 2: g2 = (z1@W2)*dinv ; z2 = dinv*(g2[n]+sum g2[src]) + b2
  hipLaunchKernelGGL((k_gemm_scale<64>),  dim3((N + 31) / 32), dim3(256), 0, stream, bufB, W2, dinv, bufA, N);
  hipLaunchKernelGGL((k_gather<false>),   dim3((N + 3) / 4),   dim3(256), 0, stream, bufA, off, perm, dinv, b2, bufB, N);
  // decoder
  hipLaunchKernelGGL(k_decode, dim3((EL + 255) / 256), dim3(256), 0, stream,
                     bufB, eli, P1t, pb1, P2, pb2, P3, pb3, out, EL);
}

// Round 2
// 308.332 us; speedup vs baseline: 1.2074x; 1.2074x over previous
//
#include <hip/hip_runtime.h>
#include <cstdint>
#include <cstddef>

#define WS_ALIGN(x) (((x) + 255) & ~(size_t)255)

#define CHUNK  4096     // edges per bucketing block
#define BSHIFT 9        // 512 nodes per coarse bucket
#define BNODES 512
#define MAXNB  512      // supports N <= 262144 (problem: N=50000 -> NB=98)
#define CAP    12288    // max edges per bucket staged in LDS (mean ~8163, sd ~90)

// ---------- pass A: per-block coarse histogram ----------
__global__ __launch_bounds__(256) void pA_hist(const int* __restrict__ dst, int* __restrict__ bh,
                                               int E, int NB, int NBLK) {
  __shared__ int hist[MAXNB];
  int t = threadIdx.x, blk = blockIdx.x;
  for (int b = t; b < NB; b += 256) hist[b] = 0;
  __syncthreads();
  int e0 = blk * CHUNK, e1 = min(E, e0 + CHUNK);
  for (int e = e0 + t; e < e1; e += 256) atomicAdd(&hist[dst[e] >> BSHIFT], 1);
  __syncthreads();
  for (int b = t; b < NB; b += 256) bh[b * NBLK + blk] = hist[b];   // bucket-major
}

// ---------- hierarchical exclusive scan of bh[M] -> scn[M] ----------
__global__ __launch_bounds__(256) void k_s1(const int* __restrict__ in, int* __restrict__ bsum, int M) {
  __shared__ int s[256];
  int t = threadIdx.x, i = blockIdx.x * 256 + t;
  s[t] = (i < M) ? in[i] : 0; __syncthreads();
  for (int d = 128; d > 0; d >>= 1) { if (t < d) s[t] += s[t + d]; __syncthreads(); }
  if (t == 0) bsum[blockIdx.x] = s[0];
}

// single block: exclusive scan of bsum[nb] -> boff ; fused: transpose P1 -> P1t
__global__ __launch_bounds__(256) void k_s2(const int* __restrict__ bsum, int* __restrict__ boff, int nb,
                                            const float* __restrict__ P1, float* __restrict__ P1t) {
  int t = threadIdx.x;
  for (int idx = t; idx < 64 * 64; idx += 256) {
    int j = idx >> 6, k = idx & 63;
    P1t[idx] = P1[k * 64 + j];
  }
  __shared__ int s[256];
  if (nb <= 256) {
    int v = (t < nb) ? bsum[t] : 0;
    s[t] = v; __syncthreads();
    for (int d = 1; d < 256; d <<= 1) {
      int add = (t >= d) ? s[t - d] : 0;
      __syncthreads(); s[t] += add; __syncthreads();
    }
    if (t < nb) boff[t] = s[t] - v;
  } else {
    if (t == 0) { int run = 0; for (int b = 0; b < nb; ++b) { boff[b] = run; run += bsum[b]; } }
  }
}

__global__ __launch_bounds__(256) void k_s3(const int* __restrict__ in, const int* __restrict__ boff,
                                            int* __restrict__ out, int M) {
  __shared__ int s[256];
  int t = threadIdx.x, i = blockIdx.x * 256 + t;
  int v = (i < M) ? in[i] : 0;
  s[t] = v; __syncthreads();
  for (int d = 1; d < 256; d <<= 1) {
    int add = (t >= d) ? s[t - d] : 0;
    __syncthreads(); s[t] += add; __syncthreads();
  }
  if (i < M) out[i] = s[t] - v + boff[blockIdx.x];
}

// ---------- pass C: bucket-sort each chunk in LDS, write (src,dst) runs contiguously ----------
__global__ __launch_bounds__(256) void pC_scatter(const int* __restrict__ ei, const int* __restrict__ scn,
                                                  int2* __restrict__ pairs, int E, int NB, int NBLK) {
  __shared__ int hist[MAXNB], gcur[MAXNB], cur[MAXNB], lscan[MAXNB + 1], inc[MAXNB];
  __shared__ unsigned short bmap[CHUNK];
  __shared__ int sSrc[CHUNK], sDst[CHUNK];
  int t = threadIdx.x, blk = blockIdx.x;
  for (int b = t; b < NB; b += 256) { hist[b] = 0; gcur[b] = scn[b * NBLK + blk]; }
  __syncthreads();
  int e0 = blk * CHUNK, e1 = min(E, e0 + CHUNK), cnt = e1 - e0;
  for (int e = e0 + t; e < e1; e += 256) atomicAdd(&hist[ei[E + e] >> BSHIFT], 1);
  __syncthreads();
  // inclusive scan of hist (padded to 512), 2 elems/thread Hillis-Steele
  {
    inc[t] = (t < NB) ? hist[t] : 0;
    inc[t + 256] = (t + 256 < NB) ? hist[t + 256] : 0;
    __syncthreads();
    for (int d = 1; d < MAXNB; d <<= 1) {
      int a0 = (t >= d) ? inc[t - d] : 0;
      int a1 = (t + 256 >= d) ? inc[t + 256 - d] : 0;
      __syncthreads();
      inc[t] += a0; inc[t + 256] += a1;
      __syncthreads();
    }
    if (t == 0) lscan[0] = 0;
    lscan[t + 1] = inc[t];
    lscan[t + 257] = inc[t + 256];
    __syncthreads();
  }
  for (int b = t; b < NB; b += 256) {
    cur[b] = lscan[b];
    for (int s = lscan[b]; s < lscan[b + 1]; ++s) bmap[s] = (unsigned short)b;
  }
  __syncthreads();
  for (int e = e0 + t; e < e1; e += 256) {
    int srcv = ei[e], dstv = ei[E + e];
    int b = dstv >> BSHIFT;
    int p = atomicAdd(&cur[b], 1);
    sSrc[p] = srcv; sDst[p] = dstv;
  }
  __syncthreads();
  for (int s = t; s < cnt; s += 256) {
    int b = bmap[s];
    int g = gcur[b] + (s - lscan[b]);
    pairs[g] = make_int2(sSrc[s], sDst[s]);
  }
}

// ---------- pass D: per-bucket fine CSR: counts -> dinv -> off -> coalesced perm ----------
__global__ __launch_bounds__(256) void pD_fine(const int2* __restrict__ pairs, const int* __restrict__ scn,
                                               int* __restrict__ perm, int* __restrict__ off,
                                               float* __restrict__ dinv, int N, int E, int NB, int NBLK) {
  __shared__ int ncnt[BNODES], ncur[BNODES];
  __shared__ int staged[CAP];
  int t = threadIdx.x, b = blockIdx.x;
  int node0 = b << BSHIFT;
  int S = scn[b * NBLK];
  int T = (b + 1 < NB) ? scn[(b + 1) * NBLK] : E;
  ncnt[t] = 0; ncnt[t + 256] = 0;
  __syncthreads();
  for (int e = S + t; e < T; e += 256) atomicAdd(&ncnt[pairs[e].y - node0], 1);
  __syncthreads();
  for (int l = t; l < BNODES; l += 256) {
    int node = node0 + l;
    if (node < N) dinv[node] = rsqrtf((float)ncnt[l] + 1.0f);   // +1 self-loop
  }
  // inclusive scan ncnt over 512
  for (int d = 1; d < BNODES; d <<= 1) {
    int a0 = (t >= d) ? ncnt[t - d] : 0;
    int a1 = (t + 256 >= d) ? ncnt[t + 256 - d] : 0;
    __syncthreads();
    ncnt[t] += a0; ncnt[t + 256] += a1;
    __syncthreads();
  }
  for (int l = t; l < BNODES; l += 256) {
    int excl = (l > 0) ? ncnt[l - 1] : 0;
    ncur[l] = excl;
    int node = node0 + l;
    if (node < N) off[node] = S + excl;
  }
  if (b == NB - 1 && t == 0) off[N] = E;
  __syncthreads();
  bool ok = (T - S) <= CAP;
  for (int e = S + t; e < T; e += 256) {
    int2 p = pairs[e];
    int pos = atomicAdd(&ncur[p.y - node0], 1);
    if (ok) staged[pos] = p.x;
    else    perm[S + pos] = p.x;     // fallback, never expected at this size
  }
  if (ok) {
    __syncthreads();
    for (int s = t; s < T - S; s += 256) perm[S + s] = staged[s];
  }
}

// ---------- GEMM: O[n][j] = (sum_k X[n][k] W[k][j]) * dinv[n] ----------
template<int K>
__global__ __launch_bounds__(256) void k_gemm_scale(const float* __restrict__ X, const float* __restrict__ W,
                                                    const float* __restrict__ dinv, float* __restrict__ O, int N) {
  __shared__ float Ws[K * 64];
  for (int idx = threadIdx.x; idx < K * 64; idx += 256) Ws[idx] = W[idx];
  __syncthreads();
  const int lane = threadIdx.x & 63;
  const int wg = threadIdx.x >> 6;
  int row0 = blockIdx.x * 32 + wg * 8;
  if (row0 > N - 8) row0 = N - 8;
  row0 = __builtin_amdgcn_readfirstlane(row0);
  const float* __restrict__ Xr = X + (size_t)row0 * K;
  float acc[8] = {0.f, 0.f, 0.f, 0.f, 0.f, 0.f, 0.f, 0.f};
  #pragma unroll 8
  for (int k = 0; k < K; ++k) {
    float w = Ws[k * 64 + lane];
    #pragma unroll
    for (int i = 0; i < 8; ++i)
      acc[i] = fmaf(Xr[(size_t)i * K + k], w, acc[i]);
  }
  #pragma unroll
  for (int i = 0; i < 8; ++i) {
    float dv = dinv[row0 + i];
    O[(size_t)(row0 + i) * 64 + lane] = acc[i] * dv;
  }
}

// ---------- aggregation gather: z[n] = dinv[n]*(g[n] + sum g[src]) + bias (opt. relu) ----------
template<bool RELU>
__global__ __launch_bounds__(256) void k_gather(const float* __restrict__ g, const int* __restrict__ off,
                                                const int* __restrict__ perm, const float* __restrict__ dinv,
                                                const float* __restrict__ bias, float* __restrict__ z, int N) {
  int lane = threadIdx.x & 63;
  int n = blockIdx.x * 4 + (threadIdx.x >> 6);
  if (n >= N) return;
  int s0 = off[n], s1 = off[n + 1];
  float a0 = g[(size_t)n * 64 + lane], a1 = 0.f, a2 = 0.f, a3 = 0.f;
  int p = s0;
  for (; p + 4 <= s1; p += 4) {
    int i0 = perm[p], i1 = perm[p + 1], i2 = perm[p + 2], i3 = perm[p + 3];
    a0 += g[(size_t)i0 * 64 + lane];
    a1 += g[(size_t)i1 * 64 + lane];
    a2 += g[(size_t)i2 * 64 + lane];
    a3 += g[(size_t)i3 * 64 + lane];
  }
  for (; p < s1; ++p) a0 += g[(size_t)perm[p] * 64 + lane];
  float r = dinv[n] * ((a0 + a1) + (a2 + a3)) + bias[lane];
  if (RELU) r = fmaxf(r, 0.f);
  z[(size_t)n * 64 + lane] = r;
}

// ---------- decoder ----------
__global__ __launch_bounds__(256) void k_decode(const float* __restrict__ z, const int* __restrict__ eli,
                                                const float* __restrict__ P1t, const float* __restrict__ pb1,
                                                const float* __restrict__ P2, const float* __restrict__ pb2,
                                                const float* __restrict__ P3, const float* __restrict__ pb3,
                                                float* __restrict__ out, int EL) {
  int e = blockIdx.x * 256 + threadIdx.x;
  if (e >= EL) return;
  int u = eli[e], v = eli[EL + e];
  const float* __restrict__ zu = z + (size_t)u * 64;
  const float* __restrict__ zv = z + (size_t)v * 64;
  float ef[64];
  #pragma unroll
  for (int k = 0; k < 64; k += 4) {
    float4 a = *(const float4*)(zu + k);
    float4 b = *(const float4*)(zv + k);
    ef[k + 0] = a.x * b.x; ef[k + 1] = a.y * b.y;
    ef[k + 2] = a.z * b.z; ef[k + 3] = a.w * b.w;
  }
  float acc2[64];
  #pragma unroll
  for (int j2 = 0; j2 < 64; ++j2) acc2[j2] = pb2[j2];
  for (int j = 0; j < 64; ++j) {
    const float* __restrict__ p1r = P1t + j * 64;
    float h0 = 0.f, h1 = 0.f, h2 = 0.f, h3 = 0.f;
    #pragma unroll
    for (int k = 0; k < 64; k += 4) {
      h0 = fmaf(ef[k + 0], p1r[k + 0], h0);
      h1 = fmaf(ef[k + 1], p1r[k + 1], h1);
      h2 = fmaf(ef[k + 2], p1r[k + 2], h2);
      h3 = fmaf(ef[k + 3], p1r[k + 3], h3);
    }
    float hj = fmaxf(pb1[j] + ((h0 + h1) + (h2 + h3)), 0.f);
    const float* __restrict__ p2r = P2 + j * 64;
    #pragma unroll
    for (int j2 = 0; j2 < 64; ++j2) acc2[j2] = fmaf(hj, p2r[j2], acc2[j2]);
  }
  float r = pb3[0];
  #pragma unroll
  for (int j2 = 0; j2 < 64; ++j2) r = fmaf(fmaxf(acc2[j2], 0.f), P3[j2], r);
  out[e] = r;
}

// ---------- host ----------
extern "C" void kernel_launch(void* const* d_in, const int* in_sizes, int n_in,
                              void* d_out, int out_size, void* d_ws, size_t ws_size,
                              hipStream_t stream) {
  const float* x   = (const float*)d_in[0];
  const int*   ei  = (const int*)d_in[1];
  const int*   eli = (const int*)d_in[2];
  const float* W1  = (const float*)d_in[3];
  const float* b1  = (const float*)d_in[4];
  const float* W2  = (const float*)d_in[5];
  const float* b2  = (const float*)d_in[6];
  const float* P1  = (const float*)d_in[7];
  const float* pb1 = (const float*)d_in[8];
  const float* P2  = (const float*)d_in[9];
  const float* pb2 = (const float*)d_in[10];
  const float* P3  = (const float*)d_in[11];
  const float* pb3 = (const float*)d_in[12];
  float* out = (float*)d_out;

  const int N  = in_sizes[0] / 128;
  const int E  = in_sizes[1] / 2;
  const int EL = in_sizes[2] / 2;

  const int NB   = (N + BNODES - 1) >> BSHIFT;       // coarse buckets (98)
  const int NBLK = (E + CHUNK - 1) / CHUNK;          // edge chunks (196)
  const int M    = NB * NBLK;                        // count-matrix size (19208)
  const int nb2  = (M + 255) / 256;                  // scan blocks (76)

  char* w = (char*)d_ws;
  auto alloc = [&](size_t bytes) { char* p = w; w += WS_ALIGN(bytes); return p; };
  int*   bh    = (int*)  alloc((size_t)M * 4);
  int*   scn   = (int*)  alloc((size_t)M * 4);
  int*   bsum  = (int*)  alloc(1024 * 4);
  int*   boff  = (int*)  alloc(1024 * 4);
  int2*  pairs = (int2*) alloc((size_t)E * 8);
  int*   perm  = (int*)  alloc((size_t)E * 4);
  int*   off   = (int*)  alloc(((size_t)N + 1) * 4);
  float* dinv  = (float*)alloc((size_t)N * 4);
  float* P1t   = (float*)alloc(4096 * 4);
  float* bufA  = (float*)alloc((size_t)N * 64 * 4);
  float* bufB  = (float*)alloc((size_t)N * 64 * 4);

  hipLaunchKernelGGL(pA_hist,    dim3(NBLK), dim3(256), 0, stream, ei + E, bh, E, NB, NBLK);
  hipLaunchKernelGGL(k_s1,       dim3(nb2),  dim3(256), 0, stream, bh, bsum, M);
  hipLaunchKernelGGL(k_s2,       dim3(1),    dim3(256), 0, stream, bsum, boff, nb2, P1, P1t);
  hipLaunchKernelGGL(k_s3,       dim3(nb2),  dim3(256), 0, stream, bh, boff, scn, M);
  hipLaunchKernelGGL(pC_scatter, dim3(NBLK), dim3(256), 0, stream, ei, scn, pairs, E, NB, NBLK);
  hipLaunchKernelGGL(pD_fine,    dim3(NB),   dim3(256), 0, stream, pairs, scn, perm, off, dinv, N, E, NB, NBLK);

  hipLaunchKernelGGL((k_gemm_scale<128>), dim3((N + 31) / 32), dim3(256), 0, stream, x, W1, dinv, bufA, N);
  hipLaunchKernelGGL((k_gather<true>),    dim3((N + 3) / 4),   dim3(256), 0, stream, bufA, off, perm, dinv, b1, bufB, N);
  hipLaunchKernelGGL((k_gemm_scale<64>),  dim3((N + 31) / 32), dim3(256), 0, stream, bufB, W2, dinv, bufA, N);
  hipLaunchKernelGGL((k_gather<false>),   dim3((N + 3) / 4),   dim3(256), 0, stream, bufA, off, perm, dinv, b2, bufB, N);
  hipLaunchKernelGGL(k_decode, dim3((EL + 255) / 256), dim3(256), 0, stream,
                     bufB, eli, P1t, pb1, P2, pb2, P3, pb3, out, EL);
}

// Round 3
// 281.466 us; speedup vs baseline: 1.3227x; 1.0954x over previous
//
#include <hip/hip_runtime.h>
#include <cstdint>
#include <cstddef>

#define WS_ALIGN(x) (((x) + 255) & ~(size_t)255)

#define CHUNK  4096     // edges per bucketing block
#define BSHIFT 9        // 512 nodes per coarse bucket
#define BNODES 512
#define MAXNB  512      // supports N <= 262144 (problem: N=50000 -> NB=98)
#define CAP    12288    // max edges per bucket staged in LDS (mean ~8163, sd ~90)

// ---------- pass A: per-block coarse histogram ----------
__global__ __launch_bounds__(256) void pA_hist(const int* __restrict__ dst, int* __restrict__ bh,
                                               int E, int NB, int NBLK) {
  __shared__ int hist[MAXNB];
  int t = threadIdx.x, blk = blockIdx.x;
  for (int b = t; b < NB; b += 256) hist[b] = 0;
  __syncthreads();
  int e0 = blk * CHUNK, e1 = min(E, e0 + CHUNK);
  for (int e = e0 + t; e < e1; e += 256) atomicAdd(&hist[dst[e] >> BSHIFT], 1);
  __syncthreads();
  for (int b = t; b < NB; b += 256) bh[b * NBLK + blk] = hist[b];   // bucket-major
}

// ---------- hierarchical exclusive scan of bh[M] -> scn[M] ----------
__global__ __launch_bounds__(256) void k_s1(const int* __restrict__ in, int* __restrict__ bsum, int M) {
  __shared__ int s[256];
  int t = threadIdx.x, i = blockIdx.x * 256 + t;
  s[t] = (i < M) ? in[i] : 0; __syncthreads();
  for (int d = 128; d > 0; d >>= 1) { if (t < d) s[t] += s[t + d]; __syncthreads(); }
  if (t == 0) bsum[blockIdx.x] = s[0];
}

// single block: exclusive scan of bsum[nb] -> boff
__global__ __launch_bounds__(256) void k_s2(const int* __restrict__ bsum, int* __restrict__ boff, int nb) {
  int t = threadIdx.x;
  __shared__ int s[256];
  if (nb <= 256) {
    int v = (t < nb) ? bsum[t] : 0;
    s[t] = v; __syncthreads();
    for (int d = 1; d < 256; d <<= 1) {
      int add = (t >= d) ? s[t - d] : 0;
      __syncthreads(); s[t] += add; __syncthreads();
    }
    if (t < nb) boff[t] = s[t] - v;
  } else {
    if (t == 0) { int run = 0; for (int b = 0; b < nb; ++b) { boff[b] = run; run += bsum[b]; } }
  }
}

__global__ __launch_bounds__(256) void k_s3(const int* __restrict__ in, const int* __restrict__ boff,
                                            int* __restrict__ out, int M) {
  __shared__ int s[256];
  int t = threadIdx.x, i = blockIdx.x * 256 + t;
  int v = (i < M) ? in[i] : 0;
  s[t] = v; __syncthreads();
  for (int d = 1; d < 256; d <<= 1) {
    int add = (t >= d) ? s[t - d] : 0;
    __syncthreads(); s[t] += add; __syncthreads();
  }
  if (i < M) out[i] = s[t] - v + boff[blockIdx.x];
}

// ---------- pass C: bucket-sort each chunk in LDS, write (src,dst) runs contiguously ----------
__global__ __launch_bounds__(256) void pC_scatter(const int* __restrict__ ei, const int* __restrict__ scn,
                                                  int2* __restrict__ pairs, int E, int NB, int NBLK) {
  __shared__ int hist[MAXNB], gcur[MAXNB], cur[MAXNB], lscan[MAXNB + 1], inc[MAXNB];
  __shared__ unsigned short bmap[CHUNK];
  __shared__ int sSrc[CHUNK], sDst[CHUNK];
  int t = threadIdx.x, blk = blockIdx.x;
  for (int b = t; b < NB; b += 256) { hist[b] = 0; gcur[b] = scn[b * NBLK + blk]; }
  __syncthreads();
  int e0 = blk * CHUNK, e1 = min(E, e0 + CHUNK), cnt = e1 - e0;
  for (int e = e0 + t; e < e1; e += 256) atomicAdd(&hist[ei[E + e] >> BSHIFT], 1);
  __syncthreads();
  {
    inc[t] = (t < NB) ? hist[t] : 0;
    inc[t + 256] = (t + 256 < NB) ? hist[t + 256] : 0;
    __syncthreads();
    for (int d = 1; d < MAXNB; d <<= 1) {
      int a0 = (t >= d) ? inc[t - d] : 0;
      int a1 = (t + 256 >= d) ? inc[t + 256 - d] : 0;
      __syncthreads();
      inc[t] += a0; inc[t + 256] += a1;
      __syncthreads();
    }
    if (t == 0) lscan[0] = 0;
    lscan[t + 1] = inc[t];
    lscan[t + 257] = inc[t + 256];
    __syncthreads();
  }
  for (int b = t; b < NB; b += 256) {
    cur[b] = lscan[b];
    for (int s = lscan[b]; s < lscan[b + 1]; ++s) bmap[s] = (unsigned short)b;
  }
  __syncthreads();
  for (int e = e0 + t; e < e1; e += 256) {
    int srcv = ei[e], dstv = ei[E + e];
    int b = dstv >> BSHIFT;
    int p = atomicAdd(&cur[b], 1);
    sSrc[p] = srcv; sDst[p] = dstv;
  }
  __syncthreads();
  for (int s = t; s < cnt; s += 256) {
    int b = bmap[s];
    int g = gcur[b] + (s - lscan[b]);
    pairs[g] = make_int2(sSrc[s], sDst[s]);
  }
}

// ---------- pass D: per-bucket fine CSR ----------
__global__ __launch_bounds__(256) void pD_fine(const int2* __restrict__ pairs, const int* __restrict__ scn,
                                               int* __restrict__ perm, int* __restrict__ off,
                                               float* __restrict__ dinv, int N, int E, int NB, int NBLK) {
  __shared__ int ncnt[BNODES], ncur[BNODES];
  __shared__ int staged[CAP];
  int t = threadIdx.x, b = blockIdx.x;
  int node0 = b << BSHIFT;
  int S = scn[b * NBLK];
  int T = (b + 1 < NB) ? scn[(b + 1) * NBLK] : E;
  ncnt[t] = 0; ncnt[t + 256] = 0;
  __syncthreads();
  for (int e = S + t; e < T; e += 256) atomicAdd(&ncnt[pairs[e].y - node0], 1);
  __syncthreads();
  for (int l = t; l < BNODES; l += 256) {
    int node = node0 + l;
    if (node < N) dinv[node] = rsqrtf((float)ncnt[l] + 1.0f);   // +1 self-loop
  }
  for (int d = 1; d < BNODES; d <<= 1) {
    int a0 = (t >= d) ? ncnt[t - d] : 0;
    int a1 = (t + 256 >= d) ? ncnt[t + 256 - d] : 0;
    __syncthreads();
    ncnt[t] += a0; ncnt[t + 256] += a1;
    __syncthreads();
  }
  for (int l = t; l < BNODES; l += 256) {
    int excl = (l > 0) ? ncnt[l - 1] : 0;
    ncur[l] = excl;
    int node = node0 + l;
    if (node < N) off[node] = S + excl;
  }
  if (b == NB - 1 && t == 0) off[N] = E;
  __syncthreads();
  bool ok = (T - S) <= CAP;
  for (int e = S + t; e < T; e += 256) {
    int2 p = pairs[e];
    int pos = atomicAdd(&ncur[p.y - node0], 1);
    if (ok) staged[pos] = p.x;
    else    perm[S + pos] = p.x;
  }
  if (ok) {
    __syncthreads();
    for (int s = t; s < T - S; s += 256) perm[S + s] = staged[s];
  }
}

// ---------- GEMM: O[n][j] = (sum_k X[n][k] W[k][j]) * dinv[n] ----------
template<int K>
__global__ __launch_bounds__(256) void k_gemm_scale(const float* __restrict__ X, const float* __restrict__ W,
                                                    const float* __restrict__ dinv, float* __restrict__ O, int N) {
  __shared__ float Ws[K * 64];
  for (int idx = threadIdx.x; idx < K * 64; idx += 256) Ws[idx] = W[idx];
  __syncthreads();
  const int lane = threadIdx.x & 63;
  const int wg = threadIdx.x >> 6;
  int row0 = blockIdx.x * 32 + wg * 8;
  if (row0 > N - 8) row0 = N - 8;
  row0 = __builtin_amdgcn_readfirstlane(row0);
  const float* __restrict__ Xr = X + (size_t)row0 * K;
  float acc[8] = {0.f, 0.f, 0.f, 0.f, 0.f, 0.f, 0.f, 0.f};
  #pragma unroll 8
  for (int k = 0; k < K; ++k) {
    float w = Ws[k * 64 + lane];
    #pragma unroll
    for (int i = 0; i < 8; ++i)
      acc[i] = fmaf(Xr[(size_t)i * K + k], w, acc[i]);
  }
  #pragma unroll
  for (int i = 0; i < 8; ++i) {
    float dv = dinv[row0 + i];
    O[(size_t)(row0 + i) * 64 + lane] = acc[i] * dv;
  }
}

// ---------- aggregation gather ----------
template<bool RELU>
__global__ __launch_bounds__(256) void k_gather(const float* __restrict__ g, const int* __restrict__ off,
                                                const int* __restrict__ perm, const float* __restrict__ dinv,
                                                const float* __restrict__ bias, float* __restrict__ z, int N) {
  int lane = threadIdx.x & 63;
  int n = blockIdx.x * 4 + (threadIdx.x >> 6);
  if (n >= N) return;
  int s0 = off[n], s1 = off[n + 1];
  float a0 = g[(size_t)n * 64 + lane], a1 = 0.f, a2 = 0.f, a3 = 0.f;
  int p = s0;
  for (; p + 4 <= s1; p += 4) {
    int i0 = perm[p], i1 = perm[p + 1], i2 = perm[p + 2], i3 = perm[p + 3];
    a0 += g[(size_t)i0 * 64 + lane];
    a1 += g[(size_t)i1 * 64 + lane];
    a2 += g[(size_t)i2 * 64 + lane];
    a3 += g[(size_t)i3 * 64 + lane];
  }
  for (; p < s1; ++p) a0 += g[(size_t)perm[p] * 64 + lane];
  float r = dinv[n] * ((a0 + a1) + (a2 + a3)) + bias[lane];
  if (RELU) r = fmaxf(r, 0.f);
  z[(size_t)n * 64 + lane] = r;
}

// ---------- decoder: block-cooperative, 64 edges/block, 4 waves = 4 feature-quarters ----------
// wave q owns output features [16q,16q+16); lane = edge. Weights via wave-uniform s_load
// of original-layout P rows; ef/h in LDS with stride 65 (2-way bank alias = free).
__global__ __launch_bounds__(256) void k_decode_fused(
    const float* __restrict__ z, const int* __restrict__ eli,
    const float* __restrict__ P1, const float* __restrict__ pb1,
    const float* __restrict__ P2, const float* __restrict__ pb2,
    const float* __restrict__ P3, const float* __restrict__ pb3,
    float* __restrict__ out, int EL) {
  __shared__ float ef[64 * 65];
  __shared__ float hs[64 * 65];
  __shared__ float part[4 * 64];
  const int t = threadIdx.x;
  const int e0 = blockIdx.x * 64;
  // phase 1: ef[e][k] = zu[k]*zv[k]; thread = (edge el, 16-feature quarter p)
  {
    int el = t >> 2, p = t & 3;
    int e = e0 + el;
    int ec = (e < EL) ? e : (EL - 1);      // tail: recompute dup, write guarded
    int u = eli[ec], v = eli[EL + ec];
    const float4* zu = (const float4*)(z + (size_t)u * 64 + p * 16);
    const float4* zv = (const float4*)(z + (size_t)v * 64 + p * 16);
    float* w = &ef[el * 65 + p * 16];
    #pragma unroll
    for (int i = 0; i < 4; ++i) {
      float4 a = zu[i], b = zv[i];
      w[4 * i + 0] = a.x * b.x; w[4 * i + 1] = a.y * b.y;
      w[4 * i + 2] = a.z * b.z; w[4 * i + 3] = a.w * b.w;
    }
  }
  __syncthreads();
  const int lane = t & 63;
  const int q = __builtin_amdgcn_readfirstlane(t >> 6);   // force wave-uniform
  float acc[16];
  // layer 1: h[lane][16q+j] = relu(pb1 + sum_k ef[lane][k] * P1[k][16q+j])
  #pragma unroll
  for (int j = 0; j < 16; ++j) acc[j] = pb1[16 * q + j];
  for (int k = 0; k < 64; ++k) {
    float efk = ef[lane * 65 + k];
    const float* __restrict__ w = P1 + k * 64 + 16 * q;   // uniform -> s_load_dwordx16
    #pragma unroll
    for (int j = 0; j < 16; ++j) acc[j] = fmaf(efk, w[j], acc[j]);
  }
  #pragma unroll
  for (int j = 0; j < 16; ++j) hs[lane * 65 + 16 * q + j] = fmaxf(acc[j], 0.f);
  __syncthreads();
  // layer 2: o[lane][16q+j] = pb2 + sum_k h[lane][k] * P2[k][16q+j]
  #pragma unroll
  for (int j = 0; j < 16; ++j) acc[j] = pb2[16 * q + j];
  for (int k = 0; k < 64; ++k) {
    float hk = hs[lane * 65 + k];
    const float* __restrict__ w = P2 + k * 64 + 16 * q;
    #pragma unroll
    for (int j = 0; j < 16; ++j) acc[j] = fmaf(hk, w[j], acc[j]);
  }
  // layer 3 partial: sum_j relu(o_j) * P3[j] over this wave's 16 j's
  float r = 0.f;
  #pragma unroll
  for (int j = 0; j < 16; ++j) r = fmaf(fmaxf(acc[j], 0.f), P3[16 * q + j], r);
  part[q * 64 + lane] = r;
  __syncthreads();
  if (t < 64) {
    int e = e0 + t;
    if (e < EL)
      out[e] = ((part[t] + part[64 + t]) + (part[128 + t] + part[192 + t])) + pb3[0];
  }
}

// ---------- host ----------
extern "C" void kernel_launch(void* const* d_in, const int* in_sizes, int n_in,
                              void* d_out, int out_size, void* d_ws, size_t ws_size,
                              hipStream_t stream) {
  const float* x   = (const float*)d_in[0];
  const int*   ei  = (const int*)d_in[1];
  const int*   eli = (const int*)d_in[2];
  const float* W1  = (const float*)d_in[3];
  const float* b1  = (const float*)d_in[4];
  const float* W2  = (const float*)d_in[5];
  const float* b2  = (const float*)d_in[6];
  const float* P1  = (const float*)d_in[7];
  const float* pb1 = (const float*)d_in[8];
  const float* P2  = (const float*)d_in[9];
  const float* pb2 = (const float*)d_in[10];
  const float* P3  = (const float*)d_in[11];
  const float* pb3 = (const float*)d_in[12];
  float* out = (float*)d_out;

  const int N  = in_sizes[0] / 128;
  const int E  = in_sizes[1] / 2;
  const int EL = in_sizes[2] / 2;

  const int NB   = (N + BNODES - 1) >> BSHIFT;
  const int NBLK = (E + CHUNK - 1) / CHUNK;
  const int M    = NB * NBLK;
  const int nb2  = (M + 255) / 256;

  char* w = (char*)d_ws;
  auto alloc = [&](size_t bytes) { char* p = w; w += WS_ALIGN(bytes); return p; };
  int*   bh    = (int*)  alloc((size_t)M * 4);
  int*   scn   = (int*)  alloc((size_t)M * 4);
  int*   bsum  = (int*)  alloc(1024 * 4);
  int*   boff  = (int*)  alloc(1024 * 4);
  int2*  pairs = (int2*) alloc((size_t)E * 8);
  int*   perm  = (int*)  alloc((size_t)E * 4);
  int*   off   = (int*)  alloc(((size_t)N + 1) * 4);
  float* dinv  = (float*)alloc((size_t)N * 4);
  float* bufA  = (float*)alloc((size_t)N * 64 * 4);
  float* bufB  = (float*)alloc((size_t)N * 64 * 4);

  hipLaunchKernelGGL(pA_hist,    dim3(NBLK), dim3(256), 0, stream, ei + E, bh, E, NB, NBLK);
  hipLaunchKernelGGL(k_s1,       dim3(nb2),  dim3(256), 0, stream, bh, bsum, M);
  hipLaunchKernelGGL(k_s2,       dim3(1),    dim3(256), 0, stream, bsum, boff, nb2);
  hipLaunchKernelGGL(k_s3,       dim3(nb2),  dim3(256), 0, stream, bh, boff, scn, M);
  hipLaunchKernelGGL(pC_scatter, dim3(NBLK), dim3(256), 0, stream, ei, scn, pairs, E, NB, NBLK);
  hipLaunchKernelGGL(pD_fine,    dim3(NB),   dim3(256), 0, stream, pairs, scn, perm, off, dinv, N, E, NB, NBLK);

  hipLaunchKernelGGL((k_gemm_scale<128>), dim3((N + 31) / 32), dim3(256), 0, stream, x, W1, dinv, bufA, N);
  hipLaunchKernelGGL((k_gather<true>),    dim3((N + 3) / 4),   dim3(256), 0, stream, bufA, off, perm, dinv, b1, bufB, N);
  hipLaunchKernelGGL((k_gemm_scale<64>),  dim3((N + 31) / 32), dim3(256), 0, stream, bufB, W2, dinv, bufA, N);
  hipLaunchKernelGGL((k_gather<false>),   dim3((N + 3) / 4),   dim3(256), 0, stream, bufA, off, perm, dinv, b2, bufB, N);
  hipLaunchKernelGGL(k_decode_fused, dim3((EL + 63) / 64), dim3(256), 0, stream,
                     bufB, eli, P1, pb1, P2, pb2, P3, pb3, out, EL);
}

// Round 4
// 271.142 us; speedup vs baseline: 1.3730x; 1.0381x over previous
//
#include <hip/hip_runtime.h>
#include <cstdint>
#include <cstddef>

#define WS_ALIGN(x) (((x) + 255) & ~(size_t)255)

#define CHUNK  4096     // edges per bucketing block
#define BSHIFT 9        // 512 nodes per coarse bucket
#define BNODES 512
#define MAXNB  512      // supports N <= 262144 (problem: N=50000 -> NB=98)
#define CAP    12288    // max edges per bucket staged in LDS (mean ~8163, sd ~90)

// ---------- pass A: per-block coarse histogram ----------
__global__ __launch_bounds__(256) void pA_hist(const int* __restrict__ dst, int* __restrict__ bh,
                                               int E, int NB, int NBLK) {
  __shared__ int hist[MAXNB];
  int t = threadIdx.x, blk = blockIdx.x;
  for (int b = t; b < NB; b += 256) hist[b] = 0;
  __syncthreads();
  int e0 = blk * CHUNK, e1 = min(E, e0 + CHUNK);
  for (int e = e0 + t; e < e1; e += 256) atomicAdd(&hist[dst[e] >> BSHIFT], 1);
  __syncthreads();
  for (int b = t; b < NB; b += 256) bh[b * NBLK + blk] = hist[b];   // bucket-major
}

// ---------- hierarchical exclusive scan of bh[M] -> scn[M] ----------
__global__ __launch_bounds__(256) void k_s1(const int* __restrict__ in, int* __restrict__ bsum, int M) {
  __shared__ int s[256];
  int t = threadIdx.x, i = blockIdx.x * 256 + t;
  s[t] = (i < M) ? in[i] : 0; __syncthreads();
  for (int d = 128; d > 0; d >>= 1) { if (t < d) s[t] += s[t + d]; __syncthreads(); }
  if (t == 0) bsum[blockIdx.x] = s[0];
}

__global__ __launch_bounds__(256) void k_s2(const int* __restrict__ bsum, int* __restrict__ boff, int nb) {
  int t = threadIdx.x;
  __shared__ int s[256];
  if (nb <= 256) {
    int v = (t < nb) ? bsum[t] : 0;
    s[t] = v; __syncthreads();
    for (int d = 1; d < 256; d <<= 1) {
      int add = (t >= d) ? s[t - d] : 0;
      __syncthreads(); s[t] += add; __syncthreads();
    }
    if (t < nb) boff[t] = s[t] - v;
  } else {
    if (t == 0) { int run = 0; for (int b = 0; b < nb; ++b) { boff[b] = run; run += bsum[b]; } }
  }
}

__global__ __launch_bounds__(256) void k_s3(const int* __restrict__ in, const int* __restrict__ boff,
                                            int* __restrict__ out, int M) {
  __shared__ int s[256];
  int t = threadIdx.x, i = blockIdx.x * 256 + t;
  int v = (i < M) ? in[i] : 0;
  s[t] = v; __syncthreads();
  for (int d = 1; d < 256; d <<= 1) {
    int add = (t >= d) ? s[t - d] : 0;
    __syncthreads(); s[t] += add; __syncthreads();
  }
  if (i < M) out[i] = s[t] - v + boff[blockIdx.x];
}

// ---------- pass C: bucket-sort each chunk in LDS, write (src,dst) runs contiguously ----------
__global__ __launch_bounds__(256) void pC_scatter(const int* __restrict__ ei, const int* __restrict__ scn,
                                                  int2* __restrict__ pairs, int E, int NB, int NBLK) {
  __shared__ int hist[MAXNB], gcur[MAXNB], cur[MAXNB], lscan[MAXNB + 1], inc[MAXNB];
  __shared__ unsigned short bmap[CHUNK];
  __shared__ int sSrc[CHUNK], sDst[CHUNK];
  int t = threadIdx.x, blk = blockIdx.x;
  for (int b = t; b < NB; b += 256) { hist[b] = 0; gcur[b] = scn[b * NBLK + blk]; }
  __syncthreads();
  int e0 = blk * CHUNK, e1 = min(E, e0 + CHUNK), cnt = e1 - e0;
  for (int e = e0 + t; e < e1; e += 256) atomicAdd(&hist[ei[E + e] >> BSHIFT], 1);
  __syncthreads();
  {
    inc[t] = (t < NB) ? hist[t] : 0;
    inc[t + 256] = (t + 256 < NB) ? hist[t + 256] : 0;
    __syncthreads();
    for (int d = 1; d < MAXNB; d <<= 1) {
      int a0 = (t >= d) ? inc[t - d] : 0;
      int a1 = (t + 256 >= d) ? inc[t + 256 - d] : 0;
      __syncthreads();
      inc[t] += a0; inc[t + 256] += a1;
      __syncthreads();
    }
    if (t == 0) lscan[0] = 0;
    lscan[t + 1] = inc[t];
    lscan[t + 257] = inc[t + 256];
    __syncthreads();
  }
  for (int b = t; b < NB; b += 256) {
    cur[b] = lscan[b];
    for (int s = lscan[b]; s < lscan[b + 1]; ++s) bmap[s] = (unsigned short)b;
  }
  __syncthreads();
  for (int e = e0 + t; e < e1; e += 256) {
    int srcv = ei[e], dstv = ei[E + e];
    int b = dstv >> BSHIFT;
    int p = atomicAdd(&cur[b], 1);
    sSrc[p] = srcv; sDst[p] = dstv;
  }
  __syncthreads();
  for (int s = t; s < cnt; s += 256) {
    int b = bmap[s];
    int g = gcur[b] + (s - lscan[b]);
    pairs[g] = make_int2(sSrc[s], sDst[s]);
  }
}

// ---------- pass D: per-bucket fine CSR ----------
__global__ __launch_bounds__(256) void pD_fine(const int2* __restrict__ pairs, const int* __restrict__ scn,
                                               int* __restrict__ perm, int* __restrict__ off,
                                               float* __restrict__ dinv, int N, int E, int NB, int NBLK) {
  __shared__ int ncnt[BNODES], ncur[BNODES];
  __shared__ int staged[CAP];
  int t = threadIdx.x, b = blockIdx.x;
  int node0 = b << BSHIFT;
  int S = scn[b * NBLK];
  int T = (b + 1 < NB) ? scn[(b + 1) * NBLK] : E;
  ncnt[t] = 0; ncnt[t + 256] = 0;
  __syncthreads();
  for (int e = S + t; e < T; e += 256) atomicAdd(&ncnt[pairs[e].y - node0], 1);
  __syncthreads();
  for (int l = t; l < BNODES; l += 256) {
    int node = node0 + l;
    if (node < N) dinv[node] = rsqrtf((float)ncnt[l] + 1.0f);   // +1 self-loop
  }
  for (int d = 1; d < BNODES; d <<= 1) {
    int a0 = (t >= d) ? ncnt[t - d] : 0;
    int a1 = (t + 256 >= d) ? ncnt[t + 256 - d] : 0;
    __syncthreads();
    ncnt[t] += a0; ncnt[t + 256] += a1;
    __syncthreads();
  }
  for (int l = t; l < BNODES; l += 256) {
    int excl = (l > 0) ? ncnt[l - 1] : 0;
    ncur[l] = excl;
    int node = node0 + l;
    if (node < N) off[node] = S + excl;
  }
  if (b == NB - 1 && t == 0) off[N] = E;
  __syncthreads();
  bool ok = (T - S) <= CAP;
  for (int e = S + t; e < T; e += 256) {
    int2 p = pairs[e];
    int pos = atomicAdd(&ncur[p.y - node0], 1);
    if (ok) staged[pos] = p.x;
    else    perm[S + pos] = p.x;
  }
  if (ok) {
    __syncthreads();
    for (int s = t; s < T - S; s += 256) perm[S + s] = staged[s];
  }
}

// ---------- GEMM (k-split): O[n][j] = (sum_k X[n][k] W[k][j]) * dinv[n] ----------
// Block = 16 rows. Wave w owns k-slice [w*K/4, (w+1)*K/4), W-slice in VGPRs (lane = col j).
// X tile staged coalesced into LDS, consumed as broadcast ds_read_b128.
// Cross-wave k-reduction through LDS partials; dinv scale fused in store.
template<int K>
__global__ __launch_bounds__(256) void k_gemm_scale(const float* __restrict__ X, const float* __restrict__ W,
                                                    const float* __restrict__ dinv, float* __restrict__ O, int N) {
  constexpr int KW = K / 4;       // k's per wave
  constexpr int R  = 16;          // rows per block
  __shared__ float4 Xs4[R * K / 4];           // 8 KB (K=128) / 4 KB (K=64)
  __shared__ float part[4][R][64];            // 16 KB
  float* Xs = (float*)Xs4;
  const int t = threadIdx.x;
  const int lane = t & 63;
  const int w = t >> 6;
  const int row0 = blockIdx.x * R;

  // W preload: lane j holds W[w*KW + i][j], coalesced across lanes, L2-resident.
  float wreg[KW];
  #pragma unroll
  for (int i = 0; i < KW; ++i)
    wreg[i] = W[(w * KW + i) * 64 + lane];

  // stage X tile, coalesced float4
  {
    const float4* __restrict__ Xg = (const float4*)(X + (size_t)row0 * K);
    const int total4 = R * K / 4;
    const int lim4 = (N - row0 >= R) ? total4 : ((N - row0) * K / 4);
    for (int i = t; i < total4; i += 256)
      Xs4[i] = (i < lim4) ? Xg[i] : make_float4(0.f, 0.f, 0.f, 0.f);
  }
  __syncthreads();

  float acc[R];
  #pragma unroll
  for (int r = 0; r < R; ++r) acc[r] = 0.f;

  // 4 independent row chains per step for FMA-latency ILP
  #pragma unroll
  for (int r0 = 0; r0 < R; r0 += 4) {
    const float4* __restrict__ x0 = (const float4*)(Xs + (size_t)(r0 + 0) * K + w * KW);
    const float4* __restrict__ x1 = (const float4*)(Xs + (size_t)(r0 + 1) * K + w * KW);
    const float4* __restrict__ x2 = (const float4*)(Xs + (size_t)(r0 + 2) * K + w * KW);
    const float4* __restrict__ x3 = (const float4*)(Xs + (size_t)(r0 + 3) * K + w * KW);
    #pragma unroll
    for (int i4 = 0; i4 < KW / 4; ++i4) {
      float4 a = x0[i4], b = x1[i4], c = x2[i4], d = x3[i4];
      acc[r0 + 0] = fmaf(a.x, wreg[4 * i4 + 0], acc[r0 + 0]);
      acc[r0 + 1] = fmaf(b.x, wreg[4 * i4 + 0], acc[r0 + 1]);
      acc[r0 + 2] = fmaf(c.x, wreg[4 * i4 + 0], acc[r0 + 2]);
      acc[r0 + 3] = fmaf(d.x, wreg[4 * i4 + 0], acc[r0 + 3]);
      acc[r0 + 0] = fmaf(a.y, wreg[4 * i4 + 1], acc[r0 + 0]);
      acc[r0 + 1] = fmaf(b.y, wreg[4 * i4 + 1], acc[r0 + 1]);
      acc[r0 + 2] = fmaf(c.y, wreg[4 * i4 + 1], acc[r0 + 2]);
      acc[r0 + 3] = fmaf(d.y, wreg[4 * i4 + 1], acc[r0 + 3]);
      acc[r0 + 0] = fmaf(a.z, wreg[4 * i4 + 2], acc[r0 + 0]);
      acc[r0 + 1] = fmaf(b.z, wreg[4 * i4 + 2], acc[r0 + 1]);
      acc[r0 + 2] = fmaf(c.z, wreg[4 * i4 + 2], acc[r0 + 2]);
      acc[r0 + 3] = fmaf(d.z, wreg[4 * i4 + 2], acc[r0 + 3]);
      acc[r0 + 0] = fmaf(a.w, wreg[4 * i4 + 3], acc[r0 + 0]);
      acc[r0 + 1] = fmaf(b.w, wreg[4 * i4 + 3], acc[r0 + 1]);
      acc[r0 + 2] = fmaf(c.w, wreg[4 * i4 + 3], acc[r0 + 2]);
      acc[r0 + 3] = fmaf(d.w, wreg[4 * i4 + 3], acc[r0 + 3]);
    }
  }

  #pragma unroll
  for (int r = 0; r < R; ++r) part[w][r][lane] = acc[r];
  __syncthreads();

  // reduce 4 partials; thread block covers rows in 4 passes; store coalesced with dinv fused
  for (int rr = w; rr < R; rr += 4) {
    float v = (part[0][rr][lane] + part[1][rr][lane]) + (part[2][rr][lane] + part[3][rr][lane]);
    int row = row0 + rr;
    if (row < N) O[(size_t)row * 64 + lane] = v * dinv[row];
  }
}

// ---------- aggregation gather ----------
template<bool RELU>
__global__ __launch_bounds__(256) void k_gather(const float* __restrict__ g, const int* __restrict__ off,
                                                const int* __restrict__ perm, const float* __restrict__ dinv,
                                                const float* __restrict__ bias, float* __restrict__ z, int N) {
  int lane = threadIdx.x & 63;
  int n = blockIdx.x * 4 + (threadIdx.x >> 6);
  if (n >= N) return;
  int s0 = off[n], s1 = off[n + 1];
  float a0 = g[(size_t)n * 64 + lane], a1 = 0.f, a2 = 0.f, a3 = 0.f;
  float a4 = 0.f, a5 = 0.f, a6 = 0.f, a7 = 0.f;
  int p = s0;
  for (; p + 8 <= s1; p += 8) {           // 8 rows in flight
    int i0 = perm[p],     i1 = perm[p + 1], i2 = perm[p + 2], i3 = perm[p + 3];
    int i4 = perm[p + 4], i5 = perm[p + 5], i6 = perm[p + 6], i7 = perm[p + 7];
    a0 += g[(size_t)i0 * 64 + lane];
    a1 += g[(size_t)i1 * 64 + lane];
    a2 += g[(size_t)i2 * 64 + lane];
    a3 += g[(size_t)i3 * 64 + lane];
    a4 += g[(size_t)i4 * 64 + lane];
    a5 += g[(size_t)i5 * 64 + lane];
    a6 += g[(size_t)i6 * 64 + lane];
    a7 += g[(size_t)i7 * 64 + lane];
  }
  for (; p < s1; ++p) a0 += g[(size_t)perm[p] * 64 + lane];
  float r = dinv[n] * (((a0 + a1) + (a2 + a3)) + ((a4 + a5) + (a6 + a7))) + bias[lane];
  if (RELU) r = fmaxf(r, 0.f);
  z[(size_t)n * 64 + lane] = r;
}

// ---------- decoder: block-cooperative, 64 edges/block, 4 waves = 4 feature-quarters ----------
__global__ __launch_bounds__(256) void k_decode_fused(
    const float* __restrict__ z, const int* __restrict__ eli,
    const float* __restrict__ P1, const float* __restrict__ pb1,
    const float* __restrict__ P2, const float* __restrict__ pb2,
    const float* __restrict__ P3, const float* __restrict__ pb3,
    float* __restrict__ out, int EL) {
  __shared__ float ef[64 * 65];
  __shared__ float hs[64 * 65];
  __shared__ float part[4 * 64];
  const int t = threadIdx.x;
  const int e0 = blockIdx.x * 64;
  {
    int el = t >> 2, p = t & 3;
    int e = e0 + el;
    int ec = (e < EL) ? e : (EL - 1);
    int u = eli[ec], v = eli[EL + ec];
    const float4* zu = (const float4*)(z + (size_t)u * 64 + p * 16);
    const float4* zv = (const float4*)(z + (size_t)v * 64 + p * 16);
    float* w = &ef[el * 65 + p * 16];
    #pragma unroll
    for (int i = 0; i < 4; ++i) {
      float4 a = zu[i], b = zv[i];
      w[4 * i + 0] = a.x * b.x; w[4 * i + 1] = a.y * b.y;
      w[4 * i + 2] = a.z * b.z; w[4 * i + 3] = a.w * b.w;
    }
  }
  __syncthreads();
  const int lane = t & 63;
  const int q = __builtin_amdgcn_readfirstlane(t >> 6);
  float acc[16];
  #pragma unroll
  for (int j = 0; j < 16; ++j) acc[j] = pb1[16 * q + j];
  for (int k = 0; k < 64; ++k) {
    float efk = ef[lane * 65 + k];
    const float* __restrict__ w = P1 + k * 64 + 16 * q;
    #pragma unroll
    for (int j = 0; j < 16; ++j) acc[j] = fmaf(efk, w[j], acc[j]);
  }
  #pragma unroll
  for (int j = 0; j < 16; ++j) hs[lane * 65 + 16 * q + j] = fmaxf(acc[j], 0.f);
  __syncthreads();
  #pragma unroll
  for (int j = 0; j < 16; ++j) acc[j] = pb2[16 * q + j];
  for (int k = 0; k < 64; ++k) {
    float hk = hs[lane * 65 + k];
    const float* __restrict__ w = P2 + k * 64 + 16 * q;
    #pragma unroll
    for (int j = 0; j < 16; ++j) acc[j] = fmaf(hk, w[j], acc[j]);
  }
  float r = 0.f;
  #pragma unroll
  for (int j = 0; j < 16; ++j) r = fmaf(fmaxf(acc[j], 0.f), P3[16 * q + j], r);
  part[q * 64 + lane] = r;
  __syncthreads();
  if (t < 64) {
    int e = e0 + t;
    if (e < EL)
      out[e] = ((part[t] + part[64 + t]) + (part[128 + t] + part[192 + t])) + pb3[0];
  }
}

// ---------- host ----------
extern "C" void kernel_launch(void* const* d_in, const int* in_sizes, int n_in,
                              void* d_out, int out_size, void* d_ws, size_t ws_size,
                              hipStream_t stream) {
  const float* x   = (const float*)d_in[0];
  const int*   ei  = (const int*)d_in[1];
  const int*   eli = (const int*)d_in[2];
  const float* W1  = (const float*)d_in[3];
  const float* b1  = (const float*)d_in[4];
  const float* W2  = (const float*)d_in[5];
  const float* b2  = (const float*)d_in[6];
  const float* P1  = (const float*)d_in[7];
  const float* pb1 = (const float*)d_in[8];
  const float* P2  = (const float*)d_in[9];
  const float* pb2 = (const float*)d_in[10];
  const float* P3  = (const float*)d_in[11];
  const float* pb3 = (const float*)d_in[12];
  float* out = (float*)d_out;

  const int N  = in_sizes[0] / 128;
  const int E  = in_sizes[1] / 2;
  const int EL = in_sizes[2] / 2;

  const int NB   = (N + BNODES - 1) >> BSHIFT;
  const int NBLK = (E + CHUNK - 1) / CHUNK;
  const int M    = NB * NBLK;
  const int nb2  = (M + 255) / 256;

  char* w = (char*)d_ws;
  auto alloc = [&](size_t bytes) { char* p = w; w += WS_ALIGN(bytes); return p; };
  int*   bh    = (int*)  alloc((size_t)M * 4);
  int*   scn   = (int*)  alloc((size_t)M * 4);
  int*   bsum  = (int*)  alloc(1024 * 4);
  int*   boff  = (int*)  alloc(1024 * 4);
  int2*  pairs = (int2*) alloc((size_t)E * 8);
  int*   perm  = (int*)  alloc((size_t)E * 4);
  int*   off   = (int*)  alloc(((size_t)N + 1) * 4);
  float* dinv  = (float*)alloc((size_t)N * 4);
  float* bufA  = (float*)alloc((size_t)N * 64 * 4);
  float* bufB  = (float*)alloc((size_t)N * 64 * 4);

  hipLaunchKernelGGL(pA_hist,    dim3(NBLK), dim3(256), 0, stream, ei + E, bh, E, NB, NBLK);
  hipLaunchKernelGGL(k_s1,       dim3(nb2),  dim3(256), 0, stream, bh, bsum, M);
  hipLaunchKernelGGL(k_s2,       dim3(1),    dim3(256), 0, stream, bsum, boff, nb2);
  hipLaunchKernelGGL(k_s3,       dim3(nb2),  dim3(256), 0, stream, bh, boff, scn, M);
  hipLaunchKernelGGL(pC_scatter, dim3(NBLK), dim3(256), 0, stream, ei, scn, pairs, E, NB, NBLK);
  hipLaunchKernelGGL(pD_fine,    dim3(NB),   dim3(256), 0, stream, pairs, scn, perm, off, dinv, N, E, NB, NBLK);

  hipLaunchKernelGGL((k_gemm_scale<128>), dim3((N + 15) / 16), dim3(256), 0, stream, x, W1, dinv, bufA, N);
  hipLaunchKernelGGL((k_gather<true>),    dim3((N + 3) / 4),   dim3(256), 0, stream, bufA, off, perm, dinv, b1, bufB, N);
  hipLaunchKernelGGL((k_gemm_scale<64>),  dim3((N + 15) / 16), dim3(256), 0, stream, bufB, W2, dinv, bufA, N);
  hipLaunchKernelGGL((k_gather<false>),   dim3((N + 3) / 4),   dim3(256), 0, stream, bufA, off, perm, dinv, b2, bufB, N);
  hipLaunchKernelGGL(k_decode_fused, dim3((EL + 63) / 64), dim3(256), 0, stream,
                     bufB, eli, P1, pb1, P2, pb2, P3, pb3, out, EL);
}